// Round 1
// baseline (1530.645 us; speedup 1.0000x reference)
//
#include <hip/hip_runtime.h>

// PairmixLayer: out[n,f,l3²+c] = Σ_{l1,l2} (Σ_k W[idx,f,k] g[n,k]) · Σ_{a,b} x[n,f,l1²+a] y[n,f,l2²+b] cg[l1,l2,l3,a,b,c]
// N=150000, F=64, K=16, 27 idx, 9-dim a/b/c spaces. All fp32 (no fp32 MFMA -> VALU kernel).
// Design: wave = 64 lanes = f; each wave handles T=4 consecutive n (amortizes the 110 KB
// weight table 4x -> 4.15 GB L2 instead of 16.6 GB). x/y/out staged through LDS so all
// global traffic is coalesced float4/dword. cg via uniform s_load (unrolled const offsets).

#define NTOT   150000
#define FDIM   64
#define KDIM   16
#define NIDX   27
#define TPW    4            // n per wave
#define NPB    16           // n per block (4 waves)

__device__ __constant__ float c_binom[16] = {
    1.f, 15.f, 105.f, 455.f, 1365.f, 3003.f, 5005.f, 6435.f,
    6435.f, 5005.f, 3003.f, 1365.f, 455.f, 105.f, 15.f, 1.f };

// ws: Wt[k][idx][f]  (16*27*64 floats = 110592 B)
__global__ void transpose_w(const float* __restrict__ w, float* __restrict__ wt) {
    int t = blockIdx.x * 256 + threadIdx.x;          // 27648 = 108*256 exact
    if (t >= NIDX * FDIM * KDIM) return;
    int k = t & 15, f = (t >> 4) & 63, idx = t >> 10;
    wt[(k * NIDX + idx) * FDIM + f] = w[t];
}

__global__ __launch_bounds__(256, 2)
void pairmix_main(const float* __restrict__ x, const float* __restrict__ y,
                  const float* __restrict__ r, const float* __restrict__ cg,
                  const float* __restrict__ wt, float* __restrict__ out)
{
    __shared__ __align__(16) float sx[4][TPW * FDIM * 9];   // 9216 B / wave
    __shared__ __align__(16) float sy[4][TPW * FDIM * 9];
    __shared__ float sg[4][TPW * KDIM];                     // g[j][k] per wave

    const int tid  = threadIdx.x;
    const int w    = tid >> 6;
    const int lane = tid & 63;                // = f
    const int nw   = blockIdx.x * NPB + w * TPW;   // first n of this wave

    // ---- stage x,y for 4 n rows (4*576 floats = 576 float4, coalesced) ----
    const float4* xs = (const float4*)(x + (size_t)nw * 576);
    const float4* ys = (const float4*)(y + (size_t)nw * 576);
    float4* sxv = (float4*)sx[w];
    float4* syv = (float4*)sy[w];
#pragma unroll
    for (int jj = 0; jj < 9; ++jj) {
        sxv[lane + 64 * jj] = xs[lane + 64 * jj];
        syv[lane + 64 * jj] = ys[lane + 64 * jj];
    }

    // ---- g: one Bernstein value per lane: j = lane>>4, k = lane&15 ----
    {
        const int j = lane >> 4, k = lane & 15;
        float u = r[nw + j] * 0.2f;
        u = fminf(fmaxf(u, 0.0f), 1.0f);
        float a = 1.0f, b = 1.0f;
        for (int i = 0; i < k; ++i)            a *= u;
        for (int i = 0; i < KDIM - 1 - k; ++i) b *= (1.0f - u);
        sg[w][lane] = c_binom[k] * a * b;     // sg[w][j*16+k]
    }
    __syncthreads();

    // ---- phase 1: mul[j][idx] = Σ_k g[j][k] * W[idx][f][k]  (Wt coalesced) ----
    float m[TPW][NIDX];
#pragma unroll
    for (int j = 0; j < TPW; ++j)
#pragma unroll
        for (int i = 0; i < NIDX; ++i) m[j][i] = 0.0f;

#pragma unroll 2
    for (int k = 0; k < KDIM; ++k) {
        const float g0 = sg[w][k];
        const float g1 = sg[w][16 + k];
        const float g2 = sg[w][32 + k];
        const float g3 = sg[w][48 + k];
        const float* wrow = wt + (size_t)(k * NIDX) * FDIM + lane;
#pragma unroll
        for (int idx = 0; idx < NIDX; ++idx) {
            const float wv = wrow[idx * FDIM];
            m[0][idx] = fmaf(g0, wv, m[0][idx]);
            m[1][idx] = fmaf(g1, wv, m[1][idx]);
            m[2][idx] = fmaf(g2, wv, m[2][idx]);
            m[3][idx] = fmaf(g3, wv, m[3][idx]);
        }
    }

    // ---- phase 2: per n, tensor-product contraction, result into sx slot ----
#pragma unroll
    for (int j = 0; j < TPW; ++j) {
        const int row = (j * 64 + lane) * 9;   // stride-9 LDS: conflict-free
        float xv[9], yv[9], o[9];
#pragma unroll
        for (int c = 0; c < 9; ++c) { xv[c] = sx[w][row + c]; yv[c] = sy[w][row + c]; o[c] = 0.0f; }

#pragma unroll
        for (int l1 = 0; l1 < 3; ++l1) {
#pragma unroll
            for (int l2 = 0; l2 < 3; ++l2) {
                const int d1 = 2 * l1 + 1, d2 = 2 * l2 + 1;
                float p[5][5];
#pragma unroll
                for (int a = 0; a < d1; ++a)
#pragma unroll
                    for (int b = 0; b < d2; ++b)
                        p[a][b] = xv[l1 * l1 + a] * yv[l2 * l2 + b];
#pragma unroll
                for (int l3 = 0; l3 < 3; ++l3) {
                    const int d3  = 2 * l3 + 1;
                    const int idx = (l1 * 3 + l2) * 3 + l3;
                    const float mm = m[j][idx];
                    const float* cgb = cg + idx * 125;   // [a*25 + b*5 + c], uniform -> s_load
#pragma unroll
                    for (int c = 0; c < d3; ++c) {
                        float tp = 0.0f;
#pragma unroll
                        for (int a = 0; a < d1; ++a)
#pragma unroll
                            for (int b = 0; b < d2; ++b)
                                tp = fmaf(p[a][b], cgb[a * 25 + b * 5 + c], tp);
                        o[l3 * l3 + c] = fmaf(mm, tp, o[l3 * l3 + c]);
                    }
                }
            }
        }
        // own-lane writeback into the (now dead) x slot for this n
#pragma unroll
        for (int c = 0; c < 9; ++c) sx[w][row + c] = o[c];
    }
    __syncthreads();

    // ---- coalesced float4 store of 4 n rows ----
    float4* od = (float4*)(out + (size_t)nw * 576);
#pragma unroll
    for (int jj = 0; jj < 9; ++jj) od[lane + 64 * jj] = sxv[lane + 64 * jj];
}

extern "C" void kernel_launch(void* const* d_in, const int* in_sizes, int n_in,
                              void* d_out, int out_size, void* d_ws, size_t ws_size,
                              hipStream_t stream) {
    const float* x  = (const float*)d_in[0];
    const float* y  = (const float*)d_in[1];
    const float* r  = (const float*)d_in[2];
    const float* wq = (const float*)d_in[3];
    const float* cg = (const float*)d_in[4];
    float* out = (float*)d_out;
    float* wt  = (float*)d_ws;                 // 110592 B needed

    transpose_w<<<108, 256, 0, stream>>>(wq, wt);
    pairmix_main<<<NTOT / NPB, 256, 0, stream>>>(x, y, r, cg, wt, out);
}

// Round 2
// 1214.460 us; speedup vs baseline: 1.2604x; 1.2604x over previous
//
#include <hip/hip_runtime.h>

// PairmixLayer: out[n,f,l3²+c] = Σ_{l1,l2} (Σ_k W[idx,f,k] g[n,k]) · Σ_{a,b} x[n,f,l1²+a] y[n,f,l2²+b] cg[l1,l2,l3,a,b,c]
// N=150000, F=64, K=16, 27 idx. All fp32 (no fp32 MFMA -> VALU kernel).
// R1: TPW 4 -> 2. LDS/block 73->37 KB => 4 blocks/CU = 16 waves/CU (~50% occ vs 23%).
// m[] register footprint halves (108->54) removing suspected scratch spill (R0 WRITE_SIZE
// was 3.3x ideal). Cost: W table (110 KB, L2-resident) re-read per 2n instead of per 4n.

#define NTOT   150000
#define FDIM   64
#define KDIM   16
#define NIDX   27
#define TPW    2            // n per wave
#define NPB    8            // n per block (4 waves)

__device__ __constant__ float c_binom[16] = {
    1.f, 15.f, 105.f, 455.f, 1365.f, 3003.f, 5005.f, 6435.f,
    6435.f, 5005.f, 3003.f, 1365.f, 455.f, 105.f, 15.f, 1.f };

// ws: Wt[k][idx][f]  (16*27*64 floats = 110592 B)
__global__ void transpose_w(const float* __restrict__ w, float* __restrict__ wt) {
    int t = blockIdx.x * 256 + threadIdx.x;          // 27648 = 108*256 exact
    if (t >= NIDX * FDIM * KDIM) return;
    int k = t & 15, f = (t >> 4) & 63, idx = t >> 10;
    wt[(k * NIDX + idx) * FDIM + f] = w[t];
}

__global__ __launch_bounds__(256, 4)
void pairmix_main(const float* __restrict__ x, const float* __restrict__ y,
                  const float* __restrict__ r, const float* __restrict__ cg,
                  const float* __restrict__ wt, float* __restrict__ out)
{
    __shared__ __align__(16) float sx[4][TPW * FDIM * 9];   // 4608 B / wave
    __shared__ __align__(16) float sy[4][TPW * FDIM * 9];
    __shared__ float sg[4][TPW * KDIM];                     // g[j][k] per wave

    const int tid  = threadIdx.x;
    const int w    = tid >> 6;
    const int lane = tid & 63;                // = f
    const int nw   = blockIdx.x * NPB + w * TPW;   // first n of this wave

    // ---- stage x,y for 2 n rows: 2*576 floats = 288 float4, coalesced ----
    const float4* xs = (const float4*)(x + (size_t)nw * 576);
    const float4* ys = (const float4*)(y + (size_t)nw * 576);
    float4* sxv = (float4*)sx[w];
    float4* syv = (float4*)sy[w];
#pragma unroll
    for (int jj = 0; jj < 4; ++jj) {
        sxv[lane + 64 * jj] = xs[lane + 64 * jj];
        syv[lane + 64 * jj] = ys[lane + 64 * jj];
    }
    if (lane < 32) {
        sxv[256 + lane] = xs[256 + lane];
        syv[256 + lane] = ys[256 + lane];
    }

    // ---- g: lanes 0..31 compute one Bernstein value each: j = lane>>4, k = lane&15 ----
    if (lane < TPW * KDIM) {
        const int j = lane >> 4, k = lane & 15;
        float u = r[nw + j] * 0.2f;
        u = fminf(fmaxf(u, 0.0f), 1.0f);
        float a = 1.0f, b = 1.0f;
        for (int i = 0; i < k; ++i)            a *= u;
        for (int i = 0; i < KDIM - 1 - k; ++i) b *= (1.0f - u);
        sg[w][lane] = c_binom[k] * a * b;     // sg[w][j*16+k]
    }
    __syncthreads();

    // ---- phase 1: mul[j][idx] = Σ_k g[j][k] * W[idx][f][k]  (Wt coalesced) ----
    float m[TPW][NIDX];
#pragma unroll
    for (int j = 0; j < TPW; ++j)
#pragma unroll
        for (int i = 0; i < NIDX; ++i) m[j][i] = 0.0f;

#pragma unroll 2
    for (int k = 0; k < KDIM; ++k) {
        const float g0 = sg[w][k];
        const float g1 = sg[w][16 + k];
        const float* wrow = wt + (size_t)(k * NIDX) * FDIM + lane;
#pragma unroll
        for (int idx = 0; idx < NIDX; ++idx) {
            const float wv = wrow[idx * FDIM];
            m[0][idx] = fmaf(g0, wv, m[0][idx]);
            m[1][idx] = fmaf(g1, wv, m[1][idx]);
        }
    }

    // ---- phase 2: per n, tensor-product contraction, result into sx slot ----
#pragma unroll
    for (int j = 0; j < TPW; ++j) {
        const int row = (j * 64 + lane) * 9;   // stride-9 LDS: conflict-free
        float xv[9], yv[9], o[9];
#pragma unroll
        for (int c = 0; c < 9; ++c) { xv[c] = sx[w][row + c]; yv[c] = sy[w][row + c]; o[c] = 0.0f; }

#pragma unroll
        for (int l1 = 0; l1 < 3; ++l1) {
#pragma unroll
            for (int l2 = 0; l2 < 3; ++l2) {
                const int d1 = 2 * l1 + 1, d2 = 2 * l2 + 1;
                float p[5][5];
#pragma unroll
                for (int a = 0; a < d1; ++a)
#pragma unroll
                    for (int b = 0; b < d2; ++b)
                        p[a][b] = xv[l1 * l1 + a] * yv[l2 * l2 + b];
#pragma unroll
                for (int l3 = 0; l3 < 3; ++l3) {
                    const int d3  = 2 * l3 + 1;
                    const int idx = (l1 * 3 + l2) * 3 + l3;
                    const float mm = m[j][idx];
                    const float* cgb = cg + idx * 125;   // [a*25 + b*5 + c], uniform -> s_load
#pragma unroll
                    for (int c = 0; c < d3; ++c) {
                        float tp = 0.0f;
#pragma unroll
                        for (int a = 0; a < d1; ++a)
#pragma unroll
                            for (int b = 0; b < d2; ++b)
                                tp = fmaf(p[a][b], cgb[a * 25 + b * 5 + c], tp);
                        o[l3 * l3 + c] = fmaf(mm, tp, o[l3 * l3 + c]);
                    }
                }
            }
        }
        // own-lane writeback into the (now dead) x slot for this n
#pragma unroll
        for (int c = 0; c < 9; ++c) sx[w][row + c] = o[c];
    }
    __syncthreads();

    // ---- coalesced float4 store of 2 n rows ----
    float4* od = (float4*)(out + (size_t)nw * 576);
#pragma unroll
    for (int jj = 0; jj < 4; ++jj) od[lane + 64 * jj] = sxv[lane + 64 * jj];
    if (lane < 32) od[256 + lane] = sxv[256 + lane];
}

extern "C" void kernel_launch(void* const* d_in, const int* in_sizes, int n_in,
                              void* d_out, int out_size, void* d_ws, size_t ws_size,
                              hipStream_t stream) {
    const float* x  = (const float*)d_in[0];
    const float* y  = (const float*)d_in[1];
    const float* r  = (const float*)d_in[2];
    const float* wq = (const float*)d_in[3];
    const float* cg = (const float*)d_in[4];
    float* out = (float*)d_out;
    float* wt  = (float*)d_ws;                 // 110592 B needed

    transpose_w<<<108, 256, 0, stream>>>(wq, wt);
    pairmix_main<<<NTOT / NPB, 256, 0, stream>>>(x, y, r, cg, wt, out);
}